// Round 1
// baseline (309.727 us; speedup 1.0000x reference)
//
#include <hip/hip_runtime.h>
#include <hip/hip_cooperative_groups.h>

namespace cg = cooperative_groups;

#define BB 4096
#define TT 750
#define NS_STRIDE 768
#define NBLK 768           // 12 x-tiles * 64 y-tiles; edge pairs folded into blocks 0..123

// ws float offsets (total < 1.3 MB)
// SYMMETRY: ns[t,k] = ns[t+k-6, 12-k], so phase A only computes k in [0,5] (k=6 is 0).
#define NSP_OFF   0                        // 12*384*64 transposed interior partials
#define EDGE_OFF  (4608 * 64)              // 124 edge partials (31 pairs x 4 chunks)
#define ENS_OFF   (EDGE_OFF + 128)         // 8448 = exp(-ns/2), layout [k][t] stride 768
#define GFLAG_OFF (ENS_OFF + 8448)         // 1 int: any(ens>0 && k!=6)   (own cacheline)
#define WACC_OFF  (GFLAG_OFF + 16)         // 1 float: window-term accumulator (own line)
#define RSLOT_OFF (WACC_OFF + 16)          // 768 per-block 0.1*sum(diff^2) partials

__global__ __launch_bounds__(256, 4) void k_fused(const float* __restrict__ a,
                                                  const float* __restrict__ a2,
                                                  float* __restrict__ ws,
                                                  float* __restrict__ out) {
    cg::grid_group grid = cg::this_grid();
    float* ns_p   = ws + NSP_OFF;
    float* edge_c = ws + EDGE_OFF;
    float* ens    = ws + ENS_OFF;
    int*   gflag  = (int*)(ws + GFLAG_OFF);
    float* wacc   = ws + WACC_OFF;
    float* rslots = ws + RSLOT_OFF;
    __shared__ float smem[2432];     // phase A tile 32x76; phase C aliases s_a4/s_a3
    __shared__ float swred[4];
    __shared__ float swred2[4];
    const int b = blockIdx.x, tid = threadIdx.x;

    if (b == 0 && tid == 0) { *gflag = 0; *wacc = 0.f; }   // before sync #1 -> ordered

    // ================= phase A: ns partials (k<6) + edges + reg term =================
    {
        const int x = b % 12, y = b / 12;
        const int t0 = x * 64, i0 = y * 64;
        const int tl = tid & 63, ig = tid >> 6;

        float acc[6] = {0.f, 0.f, 0.f, 0.f, 0.f, 0.f};
        float racc = 0.f;

        for (int h = 0; h < 2; ++h) {
            for (int l = tid; l < 32 * 74; l += 256) {
                int r = l / 74, c = l - r * 74;
                int gc = t0 - 6 + c;
                float v = 0.f;
                if (gc >= 0 && gc < TT) v = a[(i0 + h * 32 + r) * TT + gc];
                smem[r * 76 + c] = v;
            }
            __syncthreads();
            if (x == 0) {
                for (int r = ig; r < 32; r += 4) {
                    float xx = smem[r * 76 + tl + 6];
#pragma unroll
                    for (int k = 0; k < 6; ++k) {
                        float d = xx - smem[r * 76 + tl + k];
                        if (tl + k >= 6) acc[k] += d * d;
                    }
                }
            } else if (x == 11) {
                const int t = t0 + tl;
                if (t < TT) {
                    for (int r = ig; r < 32; r += 4) {
                        float xx = smem[r * 76 + tl + 6];
#pragma unroll
                        for (int k = 0; k < 6; ++k) {
                            float d = xx - smem[r * 76 + tl + k];
                            acc[k] += d * d;
                        }
                    }
                }
            } else {
                for (int r = ig; r < 32; r += 4) {
                    float xx = smem[r * 76 + tl + 6];
#pragma unroll
                    for (int k = 0; k < 6; ++k) {
                        float d = xx - smem[r * 76 + tl + k];
                        acc[k] += d * d;
                    }
                }
            }
            {
                const int t = t0 + tl;
                if (t < TT) {
                    for (int r = ig; r < 32; r += 4) {
                        float d = smem[r * 76 + tl + 6] - a2[(i0 + h * 32 + r) * TT + t];
                        racc += d * d;
                    }
                }
            }
            __syncthreads();
        }

#pragma unroll
        for (int k = 0; k < 6; ++k) smem[ig * 384 + tl * 6 + k] = acc[k];
        __syncthreads();

        for (int l = tid; l < 384; l += 256) {
            float s = smem[l] + smem[384 + l] + smem[768 + l] + smem[1152 + l];
            ns_p[(size_t)(x * 384 + l) * 64 + y] = s;
        }

        for (int off = 32; off > 0; off >>= 1) racc += __shfl_down(racc, off, 64);
        if (tl == 0) swred2[ig] = racc;
        __syncthreads();
        if (tid == 0)
            rslots[b] = 0.1f * (swred2[0] + swred2[1] + swred2[2] + swred2[3]);

        if (b < 124) {           // folded edge pairs (verified R6-R10)
            const int q = b >> 2, ch = b & 3;
            int t = 0, k = 0;
            if (q < 21) {
                int idx = q;
                for (int tt = 0; tt < 6; ++tt) {
                    int c = 6 - tt;
                    if (idx < c) { t = tt; k = idx; break; }
                    idx -= c;
                }
            } else {
                int idx = q - 21;
                for (int tt = 746; tt < 750; ++tt) {
                    int c = tt - 745;
                    if (idx < c) { t = tt; k = (11 - c) + idx; break; }
                    idx -= c;
                }
            }
            const int p = t + k;
            float s = 0.f;
            int i = ch * 1024 + tid;
#pragma unroll
            for (int it = 0; it < 4; ++it, i += 256) {
                float xv = a[i * TT + t];
                float v = (p < 6) ? a[((6 * i + p) & (BB - 1)) * TT]
                                  : a[((6 * i + (p - 755)) & (BB - 1)) * TT + (TT - 1)];
                float d = xv - v;
                s += d * d;
            }
            for (int off = 32; off > 0; off >>= 1) s += __shfl_down(s, off, 64);
            if (tl == 0) swred[ig] = s;
            __syncthreads();
            if (tid == 0)
                edge_c[q * 4 + ch] = swred[0] + swred[1] + swred[2] + swred[3];
        }
    }

    grid.sync();   // #1: all ns_p / edge_c / rslots visible

    // ====== phase B: row-sum + exp, spread over ALL blocks (11 rows each) ======
    if (tid < 176) {
        const int j = tid >> 4, l16 = tid & 15;
        const int l = b * 11 + j;            // 768*11 = 8448, exact cover
        const int k = l / NS_STRIDE;
        const int t = l - k * NS_STRIDE;
        float e = 0.f;
        if (t < TT) {
            if (k == 6) {
                e = 1.0f;                    // ns structurally 0; excluded from flag
            } else {
                int row;
                if (k < 6) {
                    row = (t >> 6) * 384 + (t & 63) * 6 + k;
                } else {
                    int q = t + k - 6;       // <= 753 < 768, rows >= 750 are zero
                    int kk = 12 - k;         // mirror: ns[t,k] = ns[t+k-6, 12-k]
                    row = (q >> 6) * 384 + (q & 63) * 6 + kk;
                }
                const float4 v = ((const float4*)(ns_p + (size_t)row * 64))[l16];
                float s = v.x + v.y + v.z + v.w;
                s += __shfl_down(s, 8, 16);
                s += __shfl_down(s, 4, 16);
                s += __shfl_down(s, 2, 16);
                s += __shfl_down(s, 1, 16);
                if (l16 == 0) {
                    const int p = t + k;
                    if (p < 6) {             // only possible for k < 6
                        int idx = t * 6 - t * (t - 1) / 2 + k;
                        s += edge_c[idx * 4 + 0] + edge_c[idx * 4 + 1] +
                             edge_c[idx * 4 + 2] + edge_c[idx * 4 + 3];
                    } else if (p >= 756) {   // only possible for k >= 7
                        int idx = 21 + (t - 746) * (t - 745) / 2 + (k - (756 - t));
                        s += edge_c[idx * 4 + 0] + edge_c[idx * 4 + 1] +
                             edge_c[idx * 4 + 2] + edge_c[idx * 4 + 3];
                    }
                    e = __expf(-0.5f * s);
                }
            }
        }
        if (l16 == 0) {
            ens[l] = e;
            if (e > 0.f && k != 6) atomicOr(gflag, 1);   // never fires in fast path
        }
    }

    grid.sync();   // #2: ens + gflag visible

    const int flag = __hip_atomic_load(gflag, __ATOMIC_ACQUIRE, __HIP_MEMORY_SCOPE_AGENT);

    if (flag != 0) {
        // ====== phase C general path (verified R4-R10), grid-uniform branch ======
        float* s_a4 = smem;            // 268 floats
        float* s_a3 = smem + 272;      // 268 floats
        const int x = b % 3;           // t-chunk
        const int y = b / 3;           // i-group
        const int t0 = x * 256;
        const int t = t0 + tid;
        float partial = 0.f;
        for (int ii = 0; ii < 16; ++ii) {
            const int i = y * 16 + ii;
            __syncthreads();
            for (int c = tid; c < 266; c += 256) {
                int p = t0 + c;
                float v4, v3;
                if (p < 6) {
                    int r = (6 * i + p) & (BB - 1);
                    v4 = a[r * TT];
                    v3 = a2[r * TT];
                } else if (p < 756) {
                    v4 = a[i * TT + p - 6];
                    v3 = a2[i * TT + p - 6];
                } else {
                    int r = (6 * i + (p - 755)) & (BB - 1);
                    v4 = a[r * TT + (TT - 1)];
                    v3 = a2[r * TT + (TT - 1)];
                }
                s_a4[c] = v4;
                s_a3[c] = v3;
            }
            __syncthreads();
            if (t < TT) {
                const float s2 = s_a3[tid + 6];
                float mw = -1e30f;
                float acc_d[11], acc_e[11];
#pragma unroll
                for (int k = 0; k < 11; ++k) {
                    float a4v = s_a4[tid + k];
                    float a3v = s_a3[tid + k];
                    int rr = (11 * i + k) & (BB - 1);
                    float tv = a[rr * TT + t];
                    mw = fmaxf(mw, tv - a4v);
                    acc_d[k] = fabsf(s2 - a3v);
                    acc_e[k] = ens[k * NS_STRIDE + t];
                }
                float g = mw * mw;                     // E_G
                float eg = __expf(-0.5f * g);          // SIGMA
                float acc = 0.f;
#pragma unroll
                for (int k = 0; k < 11; ++k) acc += fminf(acc_e[k], eg) * acc_d[k];
                partial += acc;
            }
        }
        for (int off = 32; off > 0; off >>= 1) partial += __shfl_down(partial, off, 64);
        __syncthreads();
        if ((tid & 63) == 0) swred[tid >> 6] = partial;
        __syncthreads();
        if (tid == 0) atomicAdd(wacc, swred[0] + swred[1] + swred[2] + swred[3]);
        grid.sync();   // #3 (slow path only, grid-uniform): wacc complete
    }

    // ================= finalize: block 0 only =================
    if (b == 0) {
        // fast path bit-identical to old k_D (slots were exact zeros there)
        float v = rslots[tid] + rslots[tid + 256] + rslots[tid + 512];
        for (int off = 32; off > 0; off >>= 1) v += __shfl_down(v, off, 64);
        __syncthreads();
        if ((tid & 63) == 0) swred2[tid >> 6] = v;
        __syncthreads();
        if (tid == 0) {
            float tot = swred2[0] + swred2[1] + swred2[2] + swred2[3];
            if (flag != 0)
                tot += __hip_atomic_load(wacc, __ATOMIC_ACQUIRE, __HIP_MEMORY_SCOPE_AGENT);
            out[0] = tot * (1.0f / BB);    // E_ALPHA = 1
        }
    }
}

extern "C" void kernel_launch(void* const* d_in, const int* in_sizes, int n_in,
                              void* d_out, int out_size, void* d_ws, size_t ws_size,
                              hipStream_t stream) {
    const float* a  = (const float*)d_in[0];   // actioness
    const float* a2 = (const float*)d_in[1];   // actioness_2
    float* ws  = (float*)d_ws;
    float* out = (float*)d_out;
    void* args[] = { (void*)&a, (void*)&a2, (void*)&ws, (void*)&out };
    hipLaunchCooperativeKernel(k_fused, dim3(NBLK), dim3(256), args, 0, stream);
}

// Round 2
// 100.500 us; speedup vs baseline: 3.0819x; 3.0819x over previous
//
#include <hip/hip_runtime.h>

#define BB 4096
#define TT 750
#define NBLK 768           // 12 x-tiles * 64 y-tiles; edge pairs folded into blocks 0..123

// ws float offsets
// Canonical ns: ns_c[t*6+k] for k in [0,5], t in [0,767]; k=6 is structurally 0;
// k>6 mirrors via ns[t,k] = ns_c[(t+k-6)*6 + (12-k)] (rows 750..753 hold back-edge sums).
#define NSC_OFF    0                       // 4608 floats, atomicAdd-accumulated
#define WACC_OFF   4624                    // 1 float: window-term accumulator
#define TICKET_OFF 4656                    // 1 uint: k_C completion ticket
#define ZERO_FLOATS 4688                   // memset covers [0, ZERO_FLOATS)
#define RSLOT_OFF  4688                    // 768 per-block 0.1*sum(diff^2) partials (no zeroing)

// ============ node 1: ns canonical sums (k<6, atomicAdd) + folded edges + reg term ======
__global__ __launch_bounds__(256, 4) void k_A(const float* __restrict__ a,
                                              const float* __restrict__ a2,
                                              float* __restrict__ ws) {
    float* ns_c   = ws + NSC_OFF;
    float* rslots = ws + RSLOT_OFF;
    __shared__ float smem[2432];     // tile 32x76 = 2432; reduction reuses [0,1536)
    __shared__ float swred[4];
    __shared__ float swred2[4];
    const int b = blockIdx.x, tid = threadIdx.x;
    const int x = b % 12, y = b / 12;
    const int t0 = x * 64, i0 = y * 64;
    const int tl = tid & 63, ig = tid >> 6;

    float acc[6] = {0.f, 0.f, 0.f, 0.f, 0.f, 0.f};
    float racc = 0.f;                // reg-term accumulator

    for (int h = 0; h < 2; ++h) {
        for (int l = tid; l < 32 * 74; l += 256) {
            int r = l / 74, c = l - r * 74;
            int gc = t0 - 6 + c;
            float v = 0.f;
            if (gc >= 0 && gc < TT) v = a[(i0 + h * 32 + r) * TT + gc];
            smem[r * 76 + c] = v;
        }
        __syncthreads();
        // window loop, k in [0,5] only (q = t+k-6 in [t-6, t-1])
        if (x == 0) {
            // front tile: guard q >= 0; (t,k) with t+k<6 stays 0 (edge blocks complete it)
            for (int r = ig; r < 32; r += 4) {
                float xx = smem[r * 76 + tl + 6];
#pragma unroll
                for (int k = 0; k < 6; ++k) {
                    float d = xx - smem[r * 76 + tl + k];
                    if (tl + k >= 6) acc[k] += d * d;
                }
            }
        } else if (x == 11) {
            // back tile: t >= 704; q <= 748 < TT always; only t < TT guard
            const int t = t0 + tl;
            if (t < TT) {
                for (int r = ig; r < 32; r += 4) {
                    float xx = smem[r * 76 + tl + 6];
#pragma unroll
                    for (int k = 0; k < 6; ++k) {
                        float d = xx - smem[r * 76 + tl + k];
                        acc[k] += d * d;
                    }
                }
            }
        } else {
            for (int r = ig; r < 32; r += 4) {
                float xx = smem[r * 76 + tl + 6];
#pragma unroll
                for (int k = 0; k < 6; ++k) {
                    float d = xx - smem[r * 76 + tl + k];
                    acc[k] += d * d;
                }
            }
        }
        // reg term: a[i,t] is a free LDS hit; a2 read coalesced
        {
            const int t = t0 + tl;
            if (t < TT) {
                for (int r = ig; r < 32; r += 4) {
                    float d = smem[r * 76 + tl + 6] - a2[(i0 + h * 32 + r) * TT + t];
                    racc += d * d;
                }
            }
        }
        __syncthreads();   // tile reads done before next-half overwrite / red aliasing
    }

    // reduction buffer aliases smem: red[ig][tl*6 + k], 4*384 = 1536 floats
#pragma unroll
    for (int k = 0; k < 6; ++k) smem[ig * 384 + tl * 6 + k] = acc[k];
    __syncthreads();

    // canonical accumulate: idx = x*384 + l = (t0 + l/6)*6 + l%6 = t*6 + k
    for (int l = tid; l < 384; l += 256) {
        float s = smem[l] + smem[384 + l] + smem[768 + l] + smem[1152 + l];
        atomicAdd(&ns_c[x * 384 + l], s);
    }

    // reg-term block reduction -> rslots[b] (already scaled by E_THETA)
    for (int off = 32; off > 0; off >>= 1) racc += __shfl_down(racc, off, 64);
    if (tl == 0) swred2[ig] = racc;
    __syncthreads();
    if (tid == 0)
        rslots[b] = 0.1f * (swred2[0] + swred2[1] + swred2[2] + swred2[3]);

    // folded edge work: blocks 0..123 -> pair q = b>>2, i-chunk ch = b&3 (verified R6-R10)
    if (b < 124) {
        const int q = b >> 2, ch = b & 3;
        int t = 0, k = 0;
        if (q < 21) {                       // front: t+k < 6, t-major
            int idx = q;
            for (int tt = 0; tt < 6; ++tt) {
                int c = 6 - tt;
                if (idx < c) { t = tt; k = idx; break; }
                idx -= c;
            }
        } else {                            // back: t+k >= 756
            int idx = q - 21;
            for (int tt = 746; tt < 750; ++tt) {
                int c = tt - 745;
                if (idx < c) { t = tt; k = (11 - c) + idx; break; }
                idx -= c;
            }
        }
        const int p = t + k;                // block-uniform
        float s = 0.f;
        int i = ch * 1024 + tid;
#pragma unroll
        for (int it = 0; it < 4; ++it, i += 256) {
            float xv = a[i * TT + t];
            float v = (p < 6) ? a[((6 * i + p) & (BB - 1)) * TT]
                              : a[((6 * i + (p - 755)) & (BB - 1)) * TT + (TT - 1)];
            float d = xv - v;
            s += d * d;
        }
        for (int off = 32; off > 0; off >>= 1) s += __shfl_down(s, off, 64);
        if (tl == 0) swred[ig] = s;
        __syncthreads();
        if (tid == 0) {
            // front: canonical (t,k); back: mirror canonical (t+k-6, 12-k), rows 750..753
            int ci = (p < 6) ? (t * 6 + k) : ((t + k - 6) * 6 + (12 - k));
            atomicAdd(&ns_c[ci], swred[0] + swred[1] + swred[2] + swred[3]);
        }
    }
}

// ====== node 2: window term w/ per-block flag + last-block finalize (absorbs B and D) ===
__global__ __launch_bounds__(256, 4) void k_C(const float* __restrict__ a,
                                              const float* __restrict__ a2,
                                              float* __restrict__ ws,
                                              float* __restrict__ out) {
    const float* ns_c   = ws + NSC_OFF;
    float* wacc   = ws + WACC_OFF;
    unsigned* ticket = (unsigned*)(ws + TICKET_OFF);
    const float* rslots = ws + RSLOT_OFF;
    __shared__ float s_a4[268];
    __shared__ float s_a3[268];
    __shared__ float swred[4];
    __shared__ int   sflag[4];
    __shared__ int   slast;
    const int b = blockIdx.x, tid = threadIdx.x;
    const int x = b % 3;            // t-chunk
    const int y = b / 3;            // i-group
    const int t0 = x * 256;
    const int t = t0 + tid;

    // per-thread e[k] from canonical ns (k=6 structurally 1; mirror for k>6)
    float e[11];
    bool any = false;
    if (t < TT) {
#pragma unroll
        for (int k = 0; k < 11; ++k) {
            if (k == 6) { e[k] = 1.0f; continue; }
            int ci = (k < 6) ? (t * 6 + k) : ((t + k - 6) * 6 + (12 - k));
            e[k] = __expf(-0.5f * ns_c[ci]);
            any = any || (e[k] > 0.f);
        }
    } else {
#pragma unroll
        for (int k = 0; k < 11; ++k) e[k] = 0.f;
    }
    unsigned long long anyb = __ballot(any);
    if ((tid & 63) == 0) sflag[tid >> 6] = (anyb != 0ull);
    __syncthreads();
    const int flag = sflag[0] | sflag[1] | sflag[2] | sflag[3];   // block-uniform

    if (flag != 0) {
        // general path (verified R4-R10); only e-load source changed (regs, same values)
        float partial = 0.f;
        for (int ii = 0; ii < 16; ++ii) {
            const int i = y * 16 + ii;
            __syncthreads();
            for (int c = tid; c < 266; c += 256) {
                int p = t0 + c;
                float v4, v3;
                if (p < 6) {
                    int r = (6 * i + p) & (BB - 1);
                    v4 = a[r * TT];
                    v3 = a2[r * TT];
                } else if (p < 756) {
                    v4 = a[i * TT + p - 6];
                    v3 = a2[i * TT + p - 6];
                } else {
                    int r = (6 * i + (p - 755)) & (BB - 1);
                    v4 = a[r * TT + (TT - 1)];
                    v3 = a2[r * TT + (TT - 1)];
                }
                s_a4[c] = v4;
                s_a3[c] = v3;
            }
            __syncthreads();
            if (t < TT) {
                const float s2 = s_a3[tid + 6];
                float mw = -1e30f;
                float acc_d[11];
#pragma unroll
                for (int k = 0; k < 11; ++k) {
                    float a4v = s_a4[tid + k];
                    float a3v = s_a3[tid + k];
                    int rr = (11 * i + k) & (BB - 1);
                    float tv = a[rr * TT + t];
                    mw = fmaxf(mw, tv - a4v);
                    acc_d[k] = fabsf(s2 - a3v);
                }
                float g = mw * mw;                     // E_G
                float eg = __expf(-0.5f * g);          // SIGMA
                float acc = 0.f;
#pragma unroll
                for (int k = 0; k < 11; ++k) acc += fminf(e[k], eg) * acc_d[k];
                partial += acc;
            }
        }
        for (int off = 32; off > 0; off >>= 1) partial += __shfl_down(partial, off, 64);
        if ((tid & 63) == 0) swred[tid >> 6] = partial;
        __syncthreads();
        if (tid == 0)
            atomicAdd(wacc, swred[0] + swred[1] + swred[2] + swred[3]);
    }

    // completion ticket; prior wacc add ordered by acq_rel RMW
    if (tid == 0) {
        unsigned my = __hip_atomic_fetch_add(ticket, 1u, __ATOMIC_ACQ_REL,
                                             __HIP_MEMORY_SCOPE_AGENT);
        slast = (my == NBLK - 1);
    }
    __syncthreads();

    if (slast) {
        // finalize: bit-identical fast-path association to old k_D
        float v = rslots[tid] + rslots[tid + 256] + rslots[tid + 512];
        for (int off = 32; off > 0; off >>= 1) v += __shfl_down(v, off, 64);
        if ((tid & 63) == 0) swred[tid >> 6] = v;
        __syncthreads();
        if (tid == 0) {
            float tot = swred[0] + swred[1] + swred[2] + swred[3];
            float w = __hip_atomic_load(wacc, __ATOMIC_ACQUIRE, __HIP_MEMORY_SCOPE_AGENT);
            out[0] = (tot + w) * (1.0f / BB);   // E_ALPHA = 1; fast path: w == +0.0f exact
        }
    }
}

extern "C" void kernel_launch(void* const* d_in, const int* in_sizes, int n_in,
                              void* d_out, int out_size, void* d_ws, size_t ws_size,
                              hipStream_t stream) {
    const float* a  = (const float*)d_in[0];   // actioness
    const float* a2 = (const float*)d_in[1];   // actioness_2
    float* ws  = (float*)d_ws;
    float* out = (float*)d_out;

    hipMemsetAsync(d_ws, 0, ZERO_FLOATS * sizeof(float), stream);   // ns_c + wacc + ticket
    k_A<<<NBLK, 256, 0, stream>>>(a, a2, ws);
    k_C<<<NBLK, 256, 0, stream>>>(a, a2, ws, out);
}